// Round 4
// baseline (512.281 us; speedup 1.0000x reference)
//
#include <hip/hip_runtime.h>
#include <hip/hip_bf16.h>

// B=4, T=1024, E=512, H=8.
// cast5 -> Q,K proj + Vt (=Wv.x^T) via gemm_bt -> mask_prep (bf16 transposed)
//   -> fused_attn (flash: online softmax over 4 key-tiles of 256)
//   -> out GEMM split-K=8 + reduce(+bias).
// Layouts: Q,K [b,t,h,e] ld 4096; Vt [h*e, b*t]; O [b,t,h*e];
//          Mr [b][k&15][q][k>>4] bf16 (transposed mask for vector loads).

typedef short bf16x8 __attribute__((ext_vector_type(8)));
typedef float f32x4 __attribute__((ext_vector_type(4)));

__device__ __forceinline__ unsigned short f2bf(float f) {
  unsigned int u = __float_as_uint(f);
  u += 0x7FFFu + ((u >> 16) & 1u);            // RNE, finite inputs
  return (unsigned short)(u >> 16);
}
__device__ __forceinline__ float bf2f(unsigned short s) {
  return __uint_as_float(((unsigned int)s) << 16);
}

typedef const __attribute__((address_space(1))) unsigned int* gas1_t;
typedef __attribute__((address_space(3))) unsigned int* las3_t;

__device__ __forceinline__ void gload16(const unsigned short* g, unsigned short* l) {
  __builtin_amdgcn_global_load_lds((gas1_t)g, (las3_t)l, 16, 0, 0);
}

__device__ __forceinline__ void store_val(unsigned short* p, float v) { *p = f2bf(v); }
__device__ __forceinline__ void store_val(float* p, float v) { *p = v; }

// ---------------- generic BT GEMM, 128x128 tile, BK=32, 4 waves ----------------
template<typename OutT, bool HAS_BIAS>
__global__ __launch_bounds__(256) void gemm_bt(
    const unsigned short* __restrict__ A, const unsigned short* __restrict__ B,
    OutT* __restrict__ C, const float* __restrict__ bias,
    int K, int lda, int ldb, int ldc, int zshift,
    long long sAb, long long sAh, long long sBb, long long sBh,
    long long sCb, long long sCh, float alpha)
{
  const int tid  = threadIdx.x;
  const int lane = tid & 63;
  const int wave = tid >> 6;
  const int wr = wave >> 1, wc = wave & 1;
  const int bb = blockIdx.z >> zshift, hh = blockIdx.z & ((1 << zshift) - 1);
  const long long m0 = (long long)blockIdx.y * 128;
  const long long n0 = (long long)blockIdx.x * 128;

  const unsigned short* Ab = A + bb * sAb + hh * sAh;
  const unsigned short* Bb = B + bb * sBb + hh * sBh;

  __shared__ __align__(16) unsigned short lds[8192];

  const int srow = wave * 16 + (tid & 15);
  const int skc  = ((tid >> 4) & 3) * 8;
  const unsigned short* gA = Ab + (size_t)(m0 + srow) * lda + skc;
  const unsigned short* gB = Bb + (size_t)(n0 + srow) * ldb + skc;
  const size_t aStep = (size_t)64 * lda;
  const size_t bStep = (size_t)64 * ldb;
  unsigned short* lA = lds + wave * 512;
  unsigned short* lB = lds + 4096 + wave * 512;

  f32x4 acc[4][4];
#pragma unroll
  for (int m = 0; m < 4; ++m)
#pragma unroll
    for (int n = 0; n < 4; ++n) acc[m][n] = (f32x4){0.f, 0.f, 0.f, 0.f};

  for (int k0 = 0; k0 < K; k0 += 32) {
    gload16(gA + k0,         lA);
    gload16(gA + aStep + k0, lA + 2048);
    gload16(gB + k0,         lB);
    gload16(gB + bStep + k0, lB + 2048);
    __syncthreads();

    bf16x8 af[4], bf[4];
    const bf16x8* sA = (const bf16x8*)lds;
    const bf16x8* sB = (const bf16x8*)(lds + 4096);
#pragma unroll
    for (int m = 0; m < 4; ++m) af[m] = sA[(wr * 4 + m) * 64 + lane];
#pragma unroll
    for (int n = 0; n < 4; ++n) bf[n] = sB[(wc * 4 + n) * 64 + lane];
#pragma unroll
    for (int m = 0; m < 4; ++m)
#pragma unroll
      for (int n = 0; n < 4; ++n)
        acc[m][n] = __builtin_amdgcn_mfma_f32_16x16x32_bf16(af[m], bf[n], acc[m][n], 0, 0, 0);
    __syncthreads();
  }

  OutT* Cb = C + bb * sCb + hh * sCh;
  const int r0 = (lane >> 4) * 4;
  const int cc = lane & 15;
#pragma unroll
  for (int m = 0; m < 4; ++m) {
#pragma unroll
    for (int n = 0; n < 4; ++n) {
      const long long col = n0 + wc * 64 + n * 16 + cc;
      const float bv = HAS_BIAS ? bias[col] : 0.0f;
#pragma unroll
      for (int r = 0; r < 4; ++r) {
        const long long row = m0 + wr * 64 + m * 16 + r0 + r;
        store_val(Cb + (size_t)row * ldc + col, acc[m][n][r] * alpha + bv);
      }
    }
  }
}

// ---------------- mask transpose/cast: Mr[b][k&15][q][k>>4] = bf16(mask[b][q][k]) ----------------
__global__ __launch_bounds__(256) void mask_prep(
    const float* __restrict__ mask, unsigned short* __restrict__ Mr)
{
  const int g = blockIdx.x * 256 + threadIdx.x;     // 512K threads
  const int c8 = g & 7;
  const int q  = (g >> 3) & 1023;
  const int i  = (g >> 13) & 15;
  const int b  = g >> 17;
  const float* src = mask + ((size_t)(b * 1024 + q)) * 1024 + i;
  unsigned short o[8];
#pragma unroll
  for (int cc = 0; cc < 8; ++cc)
    o[cc] = f2bf(src[(c8 * 8 + cc) * 16]);
  *(bf16x8*)(Mr + (((size_t)(b * 16 + i) * 1024 + q) * 64 + c8 * 8)) = *(bf16x8*)o;
}

// ---------------- fused flash attention ----------------
// block = (b,h) x 32 q-rows; 8 waves; 4 key-tiles of 256 (wave owns 32 keys/tile).
// LDS: Q frag-major [0,16384) elems; P-tile frag-major [16384,24576); f32 stats after.
// Online softmax: running max M / rescale F in LDS, running sums + O in registers.
__global__ __launch_bounds__(512, 4) void fused_attn(
    const unsigned short* __restrict__ Q, const unsigned short* __restrict__ K,
    const unsigned short* __restrict__ Vt, const unsigned short* __restrict__ Mr,
    unsigned short* __restrict__ O)
{
  const int tid  = threadIdx.x;
  const int lane = tid & 63, wave = tid >> 6;
  const int l15 = lane & 15, lhi = lane >> 4;
  // XCD-grouped swizzle: XCD x = n&7 handles bh in [4x,4x+4), qblk-major.
  const int n = blockIdx.x;
  const int x = n & 7, t_ = n >> 3;
  const int g = x * 4 + (t_ >> 5), p = t_ & 31;
  const int b = g >> 3, h = g & 7;
  const int q0 = p * 32;

  __shared__ __align__(16) unsigned short lds[25280];
  float* sc = (float*)(lds + 24576);    // [0,256) per-wave partials
  float* Ml = sc + 256;                 // [32] running max
  float* Fl = sc + 288;                 // [32] rescale factor
  float* Rl = sc + 320;                 // [32] 1/sum

  if (tid < 32) Ml[tid] = -1e30f;

  // stage Q 32x512 fragment-major: frag f=(m*16+es), slot=lane
#pragma unroll
  for (int c = 0; c < 4; ++c) {
    const int f = c * 8 + wave;
    const int m = f >> 4, es = f & 15;
    const unsigned short* gq = Q + ((size_t)(b * 1024 + q0 + m * 16 + l15)) * 4096
                                 + h * 512 + es * 32 + lhi * 8;
    gload16(gq, lds + f * 512);
  }

  const unsigned short* kbase = K + ((size_t)(b * 1024 + wave * 32 + l15)) * 4096
                                  + h * 512 + lhi * 8;
  const unsigned short* vbase = Vt + ((size_t)(h * 512 + wave * 64 + l15)) * 4096
                                   + b * 1024 + lhi * 8;
  const unsigned short* mbase = Mr + ((size_t)((b * 16 + l15) * 1024 + q0)) * 64 + wave * 2;

  f32x4 o[2][4];
#pragma unroll
  for (int m = 0; m < 2; ++m)
#pragma unroll
    for (int nf = 0; nf < 4; ++nf) o[m][nf] = (f32x4){0.f, 0.f, 0.f, 0.f};
  float runS[2][4];
#pragma unroll
  for (int m = 0; m < 2; ++m)
#pragma unroll
    for (int r = 0; r < 4; ++r) runS[m][r] = 0.f;

  const bf16x8* Ql = (const bf16x8*)lds;
  const bf16x8* Pl8 = (const bf16x8*)(lds + 16384);
  const float A2  = 0.044194173824159216f * 1.4426950408889634f;   // (1/sqrt(512))*log2(e)
  const float L2E = 1.4426950408889634f;

  __syncthreads();                                   // B0: Q staged, Ml init

  for (int tt = 0; tt < 4; ++tt) {
    // mask: per (m,r) one u32 = 2 bf16 (j=0 low, j=1 high) -- issued early
    unsigned int mku[2][4];
#pragma unroll
    for (int m = 0; m < 2; ++m)
#pragma unroll
      for (int r = 0; r < 4; ++r)
        mku[m][r] = *(const unsigned int*)(mbase + (m * 16 + lhi * 4 + r) * 64 + tt * 16);

    // ---- S = Q . Ktile^T (wave's 32 keys) ----
    f32x4 acc[2][2];
#pragma unroll
    for (int m = 0; m < 2; ++m)
#pragma unroll
      for (int j = 0; j < 2; ++j) acc[m][j] = (f32x4){0.f, 0.f, 0.f, 0.f};
    const unsigned short* kt = kbase + (size_t)tt * 256 * 4096;
#pragma unroll
    for (int es = 0; es < 16; ++es) {
      bf16x8 af[2], bfr[2];
      af[0] = Ql[es * 64 + lane];
      af[1] = Ql[(16 + es) * 64 + lane];
      bfr[0] = *(const bf16x8*)(kt + es * 32);
      bfr[1] = *(const bf16x8*)(kt + (size_t)16 * 4096 + es * 32);
#pragma unroll
      for (int m = 0; m < 2; ++m)
#pragma unroll
        for (int j = 0; j < 2; ++j)
          acc[m][j] = __builtin_amdgcn_mfma_f32_16x16x32_bf16(af[m], bfr[j], acc[m][j], 0, 0, 0);
    }

    // ---- logits in exp2 space (in place) ----
#pragma unroll
    for (int m = 0; m < 2; ++m)
#pragma unroll
      for (int r = 0; r < 4; ++r) {
        acc[m][0][r] = acc[m][0][r] * A2 - bf2f((unsigned short)(mku[m][r] & 0xffffu)) * L2E;
        acc[m][1][r] = acc[m][1][r] * A2 - bf2f((unsigned short)(mku[m][r] >> 16)) * L2E;
      }

    // ---- tile max per q-row (over wave's 32 keys) ----
    float tm[2][4];
#pragma unroll
    for (int m = 0; m < 2; ++m)
#pragma unroll
      for (int r = 0; r < 4; ++r) tm[m][r] = fmaxf(acc[m][0][r], acc[m][1][r]);
#pragma unroll
    for (int d = 1; d < 16; d <<= 1)
#pragma unroll
      for (int m = 0; m < 2; ++m)
#pragma unroll
        for (int r = 0; r < 4; ++r) tm[m][r] = fmaxf(tm[m][r], __shfl_xor(tm[m][r], d));
    if (l15 == 0) {
#pragma unroll
      for (int m = 0; m < 2; ++m)
#pragma unroll
        for (int r = 0; r < 4; ++r) sc[wave * 32 + m * 16 + lhi * 4 + r] = tm[m][r];
    }
    __syncthreads();                                 // B1

    if (tid < 32) {
      float v = sc[tid];
#pragma unroll
      for (int w = 1; w < 8; ++w) v = fmaxf(v, sc[w * 32 + tid]);
      const float Mo = Ml[tid];
      const float Mn = fmaxf(Mo, v);
      Fl[tid] = exp2f(Mo - Mn);
      Ml[tid] = Mn;
    }
    __syncthreads();                                 // B2

    // ---- rescale old state, P = exp2(lg - M), write P-tile ----
#pragma unroll
    for (int m = 0; m < 2; ++m)
#pragma unroll
      for (int r = 0; r < 4; ++r) {
        const int ql = m * 16 + lhi * 4 + r;
        const float Mq = Ml[ql];
        const float fq = Fl[ql];
        runS[m][r] *= fq;
#pragma unroll
        for (int nf = 0; nf < 4; ++nf) o[m][nf][r] *= fq;
#pragma unroll
        for (int j = 0; j < 2; ++j) {
          const float pv = exp2f(acc[m][j][r] - Mq);
          runS[m][r] += pv;
          lds[16384 + ((m * 8 + wave) * 64 + (j * 2 + (l15 >> 3)) * 16 + lhi * 4 + r) * 8
                    + (l15 & 7)] = f2bf(pv);
        }
      }
    __syncthreads();                                 // B3

    // ---- O += P . Vtile ; wave -> e-cols [w*64,(w+1)*64) ----
    const unsigned short* vt = vbase + tt * 256;
#pragma unroll
    for (int ks = 0; ks < 8; ++ks) {
      bf16x8 pa[2], vb[4];
#pragma unroll
      for (int m = 0; m < 2; ++m) pa[m] = Pl8[(m * 8 + ks) * 64 + lane];
#pragma unroll
      for (int nf = 0; nf < 4; ++nf)
        vb[nf] = *(const bf16x8*)(vt + (size_t)nf * 16 * 4096 + ks * 32);
#pragma unroll
      for (int m = 0; m < 2; ++m)
#pragma unroll
        for (int nf = 0; nf < 4; ++nf)
          o[m][nf] = __builtin_amdgcn_mfma_f32_16x16x32_bf16(pa[m], vb[nf], o[m][nf], 0, 0, 0);
    }
  }

  // ---- final sum across lanes/waves; normalize; store ----
#pragma unroll
  for (int d = 1; d < 16; d <<= 1)
#pragma unroll
    for (int m = 0; m < 2; ++m)
#pragma unroll
      for (int r = 0; r < 4; ++r) runS[m][r] += __shfl_xor(runS[m][r], d);
  if (l15 == 0) {
#pragma unroll
    for (int m = 0; m < 2; ++m)
#pragma unroll
      for (int r = 0; r < 4; ++r) sc[wave * 32 + m * 16 + lhi * 4 + r] = runS[m][r];
  }
  __syncthreads();                                   // B4
  if (tid < 32) {
    float s = sc[tid];
#pragma unroll
    for (int w = 1; w < 8; ++w) s += sc[w * 32 + tid];
    Rl[tid] = 1.0f / s;
  }
  __syncthreads();                                   // B5

#pragma unroll
  for (int m = 0; m < 2; ++m)
#pragma unroll
    for (int r = 0; r < 4; ++r) {
      const int ql = m * 16 + lhi * 4 + r;
      const float rinv = Rl[ql];
#pragma unroll
      for (int nf = 0; nf < 4; ++nf)
        O[((size_t)(b * 1024 + q0 + ql)) * 4096 + h * 512 + wave * 64 + nf * 16 + l15]
            = f2bf(o[m][nf][r] * rinv);
    }
}

// ---------------- split-K reduce: out = sum(partials) + bias ----------------
__global__ __launch_bounds__(256) void reduce_kernel(
    const float* __restrict__ P, const float* __restrict__ bias,
    float* __restrict__ out)
{
  const int i = blockIdx.x * 256 + threadIdx.x;
  const int col4 = i & 127;
  const float4* p4 = (const float4*)P + i;
  float4 s = p4[0];
#pragma unroll
  for (int z = 1; z < 8; ++z) {
    float4 v = p4[(size_t)z * 524288];
    s.x += v.x; s.y += v.y; s.z += v.z; s.w += v.w;
  }
  float4 b = ((const float4*)bias)[col4];
  s.x += b.x; s.y += b.y; s.z += b.z; s.w += b.w;
  ((float4*)out)[i] = s;
}

// ---------------- fused fp32 -> bf16 cast of all 5 tensors ----------------
__global__ __launch_bounds__(256) void cast5_kernel(
    const float* __restrict__ s0, const float* __restrict__ s1,
    const float* __restrict__ s2, const float* __restrict__ s3,
    const float* __restrict__ s4, unsigned short* __restrict__ dst)
{
  const int seg = blockIdx.x >> 11;
  const int off = (blockIdx.x & 2047) * 256 + threadIdx.x;
  const float* s = s0;
  if (seg == 1) s = s1; else if (seg == 2) s = s2;
  else if (seg == 3) s = s3; else if (seg == 4) s = s4;
  float4 v = ((const float4*)s)[off];
  ushort4 o;
  o.x = f2bf(v.x); o.y = f2bf(v.y); o.z = f2bf(v.z); o.w = f2bf(v.w);
  ((ushort4*)dst)[(size_t)seg * 524288 + off] = o;
}

extern "C" void kernel_launch(void* const* d_in, const int* in_sizes, int n_in,
                              void* d_out, int out_size, void* d_ws, size_t ws_size,
                              hipStream_t stream) {
  const float* x    = (const float*)d_in[0];
  const float* mask = (const float*)d_in[1];
  const float* Wk   = (const float*)d_in[2];
  const float* Wq   = (const float*)d_in[3];
  const float* Wv   = (const float*)d_in[4];
  const float* Wu   = (const float*)d_in[5];
  const float* bu   = (const float*)d_in[6];

  const size_t MB = 1024 * 1024;
  if (ws_size < 212 * MB) return;
  char* ws = (char*)d_ws;
  unsigned short* xb  = (unsigned short*)(ws + 0 * MB);    // 4MB  [4096,512]
  unsigned short* Wqb = (unsigned short*)(ws + 4 * MB);
  unsigned short* Wkb = (unsigned short*)(ws + 8 * MB);
  unsigned short* Wvb = (unsigned short*)(ws + 12 * MB);
  unsigned short* Wub = (unsigned short*)(ws + 16 * MB);
  unsigned short* Qb  = (unsigned short*)(ws + 20 * MB);   // 32MB [b,t,h,e]
  unsigned short* Kb  = (unsigned short*)(ws + 52 * MB);   // 32MB
  unsigned short* Vt  = (unsigned short*)(ws + 84 * MB);   // 32MB [h*e, b*t]
  unsigned short* Ob  = (unsigned short*)(ws + 180 * MB);  // 32MB [b,t,h*e]
  unsigned short* Mr  = (unsigned short*)(ws + 4 * MB);    // 8MB, overlays Wqb/Wkb (dead post-proj)
  float* Pk = (float*)(ws + 20 * MB);  // split-K partials overlay Qb (dead post-attn)

  cast5_kernel<<<5 * 2048, 256, 0, stream>>>(x, Wq, Wk, Wv, Wu, xb);

  // Q = x.Wq^T, K = x.Wk^T   (M=N=4096, K=512)
  gemm_bt<unsigned short, false><<<dim3(32, 32, 1), 256, 0, stream>>>(
      xb, Wqb, Qb, nullptr, 512, 512, 512, 4096, 3, 0, 0, 0, 0, 0, 0, 1.0f);
  gemm_bt<unsigned short, false><<<dim3(32, 32, 1), 256, 0, stream>>>(
      xb, Wkb, Kb, nullptr, 512, 512, 512, 4096, 3, 0, 0, 0, 0, 0, 0, 1.0f);
  // Vt = Wv.x^T
  gemm_bt<unsigned short, false><<<dim3(32, 32, 1), 256, 0, stream>>>(
      Wvb, xb, Vt, nullptr, 512, 512, 512, 4096, 3, 0, 0, 0, 0, 0, 0, 1.0f);

  // transposed bf16 mask (after projections; overlays dead Wqb/Wkb)
  mask_prep<<<2048, 256, 0, stream>>>(mask, Mr);

  // fused flash attention: 1024 blocks = 32 qblk x 32 bh (XCD-grouped)
  fused_attn<<<1024, 512, 0, stream>>>(Qb, Kb, Vt, Mr, Ob);

  // out partials: split-K=8 over K=4096
  gemm_bt<float, false><<<dim3(4, 32, 8), 256, 0, stream>>>(
      Ob, Wub, Pk, nullptr, 512, 4096, 4096, 512, 0,
      512LL, 0, 512LL, 0, 2097152LL, 0, 1.0f);
  reduce_kernel<<<2048, 256, 0, stream>>>(Pk, bu, (float*)d_out);
}

// Round 5
// 416.380 us; speedup vs baseline: 1.2303x; 1.2303x over previous
//
#include <hip/hip_runtime.h>
#include <hip/hip_bf16.h>

// B=4, T=1024, E=512, H=8.
// cast5 -> Q,K proj + Vt (=Wv.x^T) via gemm_bt -> mask_cast (bf16)
//   -> fused_attn (flash, swapped-QK^T, wave-local softmax, LDS-staged K/V)
//   -> out GEMM split-K=8 + reduce(+bias).
// Layouts: Q,K [b,t,h,e] ld 4096; Vt [h*e, b*t]; O [b,t,h*e]; M2 [b,q,k] bf16.

typedef short bf16x8 __attribute__((ext_vector_type(8)));
typedef float f32x4 __attribute__((ext_vector_type(4)));

__device__ __forceinline__ unsigned short f2bf(float f) {
  unsigned int u = __float_as_uint(f);
  u += 0x7FFFu + ((u >> 16) & 1u);            // RNE, finite inputs
  return (unsigned short)(u >> 16);
}
__device__ __forceinline__ float bf2f(unsigned short s) {
  return __uint_as_float(((unsigned int)s) << 16);
}

typedef const __attribute__((address_space(1))) unsigned int* gas1_t;
typedef __attribute__((address_space(3))) unsigned int* las3_t;

__device__ __forceinline__ void gload16(const unsigned short* g, unsigned short* l) {
  __builtin_amdgcn_global_load_lds((gas1_t)g, (las3_t)l, 16, 0, 0);
}

__device__ __forceinline__ void store_val(unsigned short* p, float v) { *p = f2bf(v); }
__device__ __forceinline__ void store_val(float* p, float v) { *p = v; }

// ---------------- generic BT GEMM, 128x128 tile, BK=32, 4 waves ----------------
template<typename OutT, bool HAS_BIAS>
__global__ __launch_bounds__(256) void gemm_bt(
    const unsigned short* __restrict__ A, const unsigned short* __restrict__ B,
    OutT* __restrict__ C, const float* __restrict__ bias,
    int K, int lda, int ldb, int ldc, int zshift,
    long long sAb, long long sAh, long long sBb, long long sBh,
    long long sCb, long long sCh, float alpha)
{
  const int tid  = threadIdx.x;
  const int lane = tid & 63;
  const int wave = tid >> 6;
  const int wr = wave >> 1, wc = wave & 1;
  const int bb = blockIdx.z >> zshift, hh = blockIdx.z & ((1 << zshift) - 1);
  const long long m0 = (long long)blockIdx.y * 128;
  const long long n0 = (long long)blockIdx.x * 128;

  const unsigned short* Ab = A + bb * sAb + hh * sAh;
  const unsigned short* Bb = B + bb * sBb + hh * sBh;

  __shared__ __align__(16) unsigned short lds[8192];

  const int srow = wave * 16 + (tid & 15);
  const int skc  = ((tid >> 4) & 3) * 8;
  const unsigned short* gA = Ab + (size_t)(m0 + srow) * lda + skc;
  const unsigned short* gB = Bb + (size_t)(n0 + srow) * ldb + skc;
  const size_t aStep = (size_t)64 * lda;
  const size_t bStep = (size_t)64 * ldb;
  unsigned short* lA = lds + wave * 512;
  unsigned short* lB = lds + 4096 + wave * 512;

  f32x4 acc[4][4];
#pragma unroll
  for (int m = 0; m < 4; ++m)
#pragma unroll
    for (int n = 0; n < 4; ++n) acc[m][n] = (f32x4){0.f, 0.f, 0.f, 0.f};

  for (int k0 = 0; k0 < K; k0 += 32) {
    gload16(gA + k0,         lA);
    gload16(gA + aStep + k0, lA + 2048);
    gload16(gB + k0,         lB);
    gload16(gB + bStep + k0, lB + 2048);
    __syncthreads();

    bf16x8 af[4], bf[4];
    const bf16x8* sA = (const bf16x8*)lds;
    const bf16x8* sB = (const bf16x8*)(lds + 4096);
#pragma unroll
    for (int m = 0; m < 4; ++m) af[m] = sA[(wr * 4 + m) * 64 + lane];
#pragma unroll
    for (int n = 0; n < 4; ++n) bf[n] = sB[(wc * 4 + n) * 64 + lane];
#pragma unroll
    for (int m = 0; m < 4; ++m)
#pragma unroll
      for (int n = 0; n < 4; ++n)
        acc[m][n] = __builtin_amdgcn_mfma_f32_16x16x32_bf16(af[m], bf[n], acc[m][n], 0, 0, 0);
    __syncthreads();
  }

  OutT* Cb = C + bb * sCb + hh * sCh;
  const int r0 = (lane >> 4) * 4;
  const int cc = lane & 15;
#pragma unroll
  for (int m = 0; m < 4; ++m) {
#pragma unroll
    for (int n = 0; n < 4; ++n) {
      const long long col = n0 + wc * 64 + n * 16 + cc;
      const float bv = HAS_BIAS ? bias[col] : 0.0f;
#pragma unroll
      for (int r = 0; r < 4; ++r) {
        const long long row = m0 + wr * 64 + m * 16 + r0 + r;
        store_val(Cb + (size_t)row * ldc + col, acc[m][n][r] * alpha + bv);
      }
    }
  }
}

// ---------------- fused flash attention (swapped QK^T) ----------------
// Block = (b,h) x 128 q-rows; 8 waves, wave owns 16 q (q = q0+wave*16+l15).
// 8 key-tiles of 128. S^T = mfma(K,Q): lane holds S[q=l15][32 keys].
// Softmax wave-local; P via in-wave LDS roundtrip; O^T accum in 128 VGPR.
// LDS (elems): K 2x16384 [0,32768) | V 3x8192 [32768,57344) | P 8x2176 [57344,74752)
__global__ __launch_bounds__(512, 2) void fused_attn(
    const unsigned short* __restrict__ Q, const unsigned short* __restrict__ K,
    const unsigned short* __restrict__ Vt, const unsigned short* __restrict__ M2,
    unsigned short* __restrict__ O)
{
  const int tid  = threadIdx.x;
  const int lane = tid & 63, wave = tid >> 6;
  const int l15 = lane & 15, lhi = lane >> 4;
  const int n = blockIdx.x;
  const int bh = (n & 7) * 4 + ((n >> 3) >> 3);      // XCD-pinned: 4 bh per XCD
  const int qblk = (n >> 3) & 7;
  const int b = bh >> 3, h = bh & 7;
  const int q0 = qblk * 128;

  __shared__ __align__(16) unsigned short lds[74752];   // 149504 B

  const int qrow = b * 1024 + q0 + wave * 16 + l15;
  const unsigned short* Qp = Q + (size_t)qrow * 4096 + h * 512 + lhi * 8;
  const unsigned short* Kb = K + ((size_t)(b * 1024)) * 4096 + h * 512;
  const unsigned short* Vb = Vt + ((size_t)(h * 512)) * 4096 + b * 1024;
  const unsigned short* Mp = M2 + (size_t)qrow * 1024;
  unsigned short* Pw = lds + 57344 + wave * 2176 + l15 * 136;

  // stage K slice s (4 es-steps x 8 key-groups = 32 frags) of tile t into buf par
  auto stageK = [&](int par, int t, int s) {
#pragma unroll
    for (int c = 0; c < 4; ++c) {
      const int f = wave * 4 + c;
      const int es_l = f >> 3, kg = f & 7;
      const unsigned short* src = Kb + (size_t)(t * 128 + kg * 16 + l15) * 4096
                                     + (s * 4 + es_l) * 32 + lhi * 8;
      gload16(src, lds + par * 16384 + f * 512);
    }
  };
  // stage V slice vs (4 e-groups x 4 k-steps = 16 frags) of tile t into buf par
  auto stageV = [&](int par, int t, int vs) {
#pragma unroll
    for (int c = 0; c < 2; ++c) {
      const int f = wave * 2 + c;
      const int eg_l = f >> 2, ks = f & 3;
      const unsigned short* src = Vb + (size_t)((vs * 4 + eg_l) * 16 + l15) * 4096
                                     + t * 128 + ks * 32 + lhi * 8;
      gload16(src, lds + 32768 + par * 8192 + f * 512);
    }
  };

  f32x4 o[32];
#pragma unroll
  for (int eg = 0; eg < 32; ++eg) o[eg] = (f32x4){0.f, 0.f, 0.f, 0.f};
  float Mo = -3.0e38f, runS = 0.f;

  const float A2  = 0.044194173824159216f * 1.4426950408889634f;
  const float L2E = 1.4426950408889634f;

  stageK(0, 0, 0);
  __syncthreads();

  for (int t = 0; t < 8; ++t) {
    // mask: 8 x 8B vector loads (4 bf16 each) for this lane's q-row
    uint2 mk[8];
#pragma unroll
    for (int kg = 0; kg < 8; ++kg)
      mk[kg] = *(const uint2*)(Mp + t * 128 + kg * 16 + lhi * 4);

    // ---- QK^T phase: 4 K-slices ----
    f32x4 acc[8];
#pragma unroll
    for (int kg = 0; kg < 8; ++kg) acc[kg] = (f32x4){0.f, 0.f, 0.f, 0.f};
#pragma unroll
    for (int s = 0; s < 4; ++s) {
      if (s < 3) stageK((s + 1) & 1, t, s + 1);
      if (s == 2) stageV(0, t, 0);
      if (s == 3) stageV(1, t, 1);
      const unsigned short* kb = lds + (s & 1) * 16384;
#pragma unroll
      for (int es_l = 0; es_l < 4; ++es_l) {
        const bf16x8 qf = *(const bf16x8*)(Qp + (s * 4 + es_l) * 32);
#pragma unroll
        for (int kg = 0; kg < 8; ++kg) {
          const bf16x8 af = *(const bf16x8*)(kb + (es_l * 8 + kg) * 512 + lane * 8);
          acc[kg] = __builtin_amdgcn_mfma_f32_16x16x32_bf16(af, qf, acc[kg], 0, 0, 0);
        }
      }
      __syncthreads();
    }

    // ---- wave-local online softmax (exp2 space) ----
    float lg[32];
#pragma unroll
    for (int kg = 0; kg < 8; ++kg) {
      lg[kg * 4 + 0] = acc[kg][0] * A2 - bf2f((unsigned short)(mk[kg].x & 0xffffu)) * L2E;
      lg[kg * 4 + 1] = acc[kg][1] * A2 - bf2f((unsigned short)(mk[kg].x >> 16)) * L2E;
      lg[kg * 4 + 2] = acc[kg][2] * A2 - bf2f((unsigned short)(mk[kg].y & 0xffffu)) * L2E;
      lg[kg * 4 + 3] = acc[kg][3] * A2 - bf2f((unsigned short)(mk[kg].y >> 16)) * L2E;
    }
    float tm = lg[0];
#pragma unroll
    for (int j = 1; j < 32; ++j) tm = fmaxf(tm, lg[j]);
    tm = fmaxf(tm, __shfl_xor(tm, 16));
    tm = fmaxf(tm, __shfl_xor(tm, 32));
    const float Mn = fmaxf(Mo, tm);
    const float fsc = exp2f(Mo - Mn);
    Mo = Mn;
    runS *= fsc;
#pragma unroll
    for (int eg = 0; eg < 32; ++eg) o[eg] *= fsc;

    float ps = 0.f;
#pragma unroll
    for (int kg = 0; kg < 8; ++kg) {
      const float p0 = exp2f(lg[kg * 4 + 0] - Mn);
      const float p1 = exp2f(lg[kg * 4 + 1] - Mn);
      const float p2 = exp2f(lg[kg * 4 + 2] - Mn);
      const float p3 = exp2f(lg[kg * 4 + 3] - Mn);
      ps += (p0 + p1) + (p2 + p3);
      uint2 w;
      w.x = (unsigned int)f2bf(p0) | ((unsigned int)f2bf(p1) << 16);
      w.y = (unsigned int)f2bf(p2) | ((unsigned int)f2bf(p3) << 16);
      *(uint2*)(Pw + kg * 16 + lhi * 4) = w;     // P[q=l15][key], in-wave
    }
    runS += ps;

    bf16x8 pb[4];
#pragma unroll
    for (int ks = 0; ks < 4; ++ks)
      pb[ks] = *(const bf16x8*)(Pw + ks * 32 + lhi * 8);   // same-wave RAW, DS in-order

    // ---- PV phase: 8 V-slices (3-buf, staged 2 ahead) ----
#pragma unroll
    for (int vs = 0; vs < 8; ++vs) {
      if (vs < 6) stageV((vs + 2) % 3, t, vs + 2);
      if (vs == 6 && t != 7) stageK(0, t + 1, 0);
      const unsigned short* vb = lds + 32768 + (vs % 3) * 8192;
#pragma unroll
      for (int eg_l = 0; eg_l < 4; ++eg_l)
#pragma unroll
        for (int ks = 0; ks < 4; ++ks) {
          const bf16x8 af = *(const bf16x8*)(vb + (eg_l * 4 + ks) * 512 + lane * 8);
          o[vs * 4 + eg_l] = __builtin_amdgcn_mfma_f32_16x16x32_bf16(af, pb[ks], o[vs * 4 + eg_l], 0, 0, 0);
        }
      __syncthreads();
    }
  }

  // ---- epilogue: row sums across lhi groups, normalize, store O^T as O[q, e] ----
  runS += __shfl_xor(runS, 16);
  runS += __shfl_xor(runS, 32);
  const float rinv = 1.0f / runS;
  unsigned short* Op = O + (size_t)qrow * 4096 + h * 512 + lhi * 4;
#pragma unroll
  for (int eg = 0; eg < 32; ++eg) {
    uint2 w;
    w.x = (unsigned int)f2bf(o[eg][0] * rinv) | ((unsigned int)f2bf(o[eg][1] * rinv) << 16);
    w.y = (unsigned int)f2bf(o[eg][2] * rinv) | ((unsigned int)f2bf(o[eg][3] * rinv) << 16);
    *(uint2*)(Op + eg * 16) = w;
  }
}

// ---------------- split-K reduce: out = sum(partials) + bias ----------------
__global__ __launch_bounds__(256) void reduce_kernel(
    const float* __restrict__ P, const float* __restrict__ bias,
    float* __restrict__ out)
{
  const int i = blockIdx.x * 256 + threadIdx.x;
  const int col4 = i & 127;
  const float4* p4 = (const float4*)P + i;
  float4 s = p4[0];
#pragma unroll
  for (int z = 1; z < 8; ++z) {
    float4 v = p4[(size_t)z * 524288];
    s.x += v.x; s.y += v.y; s.z += v.z; s.w += v.w;
  }
  float4 b = ((const float4*)bias)[col4];
  s.x += b.x; s.y += b.y; s.z += b.z; s.w += b.w;
  ((float4*)out)[i] = s;
}

// ---------------- fused fp32 -> bf16 cast of all 5 tensors ----------------
__global__ __launch_bounds__(256) void cast5_kernel(
    const float* __restrict__ s0, const float* __restrict__ s1,
    const float* __restrict__ s2, const float* __restrict__ s3,
    const float* __restrict__ s4, unsigned short* __restrict__ dst)
{
  const int seg = blockIdx.x >> 11;
  const int off = (blockIdx.x & 2047) * 256 + threadIdx.x;
  const float* s = s0;
  if (seg == 1) s = s1; else if (seg == 2) s = s2;
  else if (seg == 3) s = s3; else if (seg == 4) s = s4;
  float4 v = ((const float4*)s)[off];
  ushort4 o;
  o.x = f2bf(v.x); o.y = f2bf(v.y); o.z = f2bf(v.z); o.w = f2bf(v.w);
  ((ushort4*)dst)[(size_t)seg * 524288 + off] = o;
}

// ---------------- mask fp32 -> bf16 cast ----------------
__global__ __launch_bounds__(256) void mask_cast(
    const float* __restrict__ mask, unsigned short* __restrict__ M2)
{
  const int i = blockIdx.x * 256 + threadIdx.x;   // 1M float4
  float4 v = ((const float4*)mask)[i];
  ushort4 o;
  o.x = f2bf(v.x); o.y = f2bf(v.y); o.z = f2bf(v.z); o.w = f2bf(v.w);
  ((ushort4*)M2)[i] = o;
}

extern "C" void kernel_launch(void* const* d_in, const int* in_sizes, int n_in,
                              void* d_out, int out_size, void* d_ws, size_t ws_size,
                              hipStream_t stream) {
  const float* x    = (const float*)d_in[0];
  const float* mask = (const float*)d_in[1];
  const float* Wk   = (const float*)d_in[2];
  const float* Wq   = (const float*)d_in[3];
  const float* Wv   = (const float*)d_in[4];
  const float* Wu   = (const float*)d_in[5];
  const float* bu   = (const float*)d_in[6];

  const size_t MB = 1024 * 1024;
  if (ws_size < 212 * MB) return;
  char* ws = (char*)d_ws;
  unsigned short* xb  = (unsigned short*)(ws + 0 * MB);    // 4MB  [4096,512]
  unsigned short* Wqb = (unsigned short*)(ws + 4 * MB);
  unsigned short* Wkb = (unsigned short*)(ws + 8 * MB);
  unsigned short* Wvb = (unsigned short*)(ws + 12 * MB);
  unsigned short* Wub = (unsigned short*)(ws + 16 * MB);
  unsigned short* Qb  = (unsigned short*)(ws + 20 * MB);   // 32MB [b,t,h,e]
  unsigned short* Kb  = (unsigned short*)(ws + 52 * MB);   // 32MB
  unsigned short* Vt  = (unsigned short*)(ws + 84 * MB);   // 32MB [h*e, b*t]
  unsigned short* Ob  = (unsigned short*)(ws + 180 * MB);  // 32MB [b,t,h*e]
  unsigned short* M2  = (unsigned short*)(ws + 4 * MB);    // 8MB, overlays Wqb/Wkb (dead post-proj)
  float* Pk = (float*)(ws + 20 * MB);  // split-K partials overlay Qb/Kb (dead post-attn)

  cast5_kernel<<<5 * 2048, 256, 0, stream>>>(x, Wq, Wk, Wv, Wu, xb);

  // Q = x.Wq^T, K = x.Wk^T   (M=N=4096, K=512)
  gemm_bt<unsigned short, false><<<dim3(32, 32, 1), 256, 0, stream>>>(
      xb, Wqb, Qb, nullptr, 512, 512, 512, 4096, 3, 0, 0, 0, 0, 0, 0, 1.0f);
  gemm_bt<unsigned short, false><<<dim3(32, 32, 1), 256, 0, stream>>>(
      xb, Wkb, Kb, nullptr, 512, 512, 512, 4096, 3, 0, 0, 0, 0, 0, 0, 1.0f);
  // Vt = Wv.x^T
  gemm_bt<unsigned short, false><<<dim3(32, 32, 1), 256, 0, stream>>>(
      Wvb, xb, Vt, nullptr, 512, 512, 512, 4096, 3, 0, 0, 0, 0, 0, 0, 1.0f);

  // bf16 mask (after projections; overlays dead Wqb/Wkb)
  mask_cast<<<4096, 256, 0, stream>>>(mask, M2);

  // fused flash attention: 256 blocks (1/CU), 512 threads
  fused_attn<<<256, 512, 0, stream>>>(Qb, Kb, Vt, M2, Ob);

  // out partials: split-K=8 over K=4096
  gemm_bt<float, false><<<dim3(4, 32, 8), 256, 0, stream>>>(
      Ob, Wub, Pk, nullptr, 512, 4096, 4096, 512, 0,
      512LL, 0, 512LL, 0, 2097152LL, 0, 1.0f);
  reduce_kernel<<<2048, 256, 0, stream>>>(Pk, bu, (float*)d_out);
}